// Round 4
// baseline (388.709 us; speedup 1.0000x reference)
//
#include <hip/hip_runtime.h>

// ---------------- problem constants ----------------
#define F_BINS 257
#define NCH    8
#define NSRC   2
#define KW     5
#define HCH    32
#define TLEN   2000
#define BATCH  4

// ---------------- tiling ----------------
#define TT      128
#define NTILES  16          // 16*128 = 2048 >= 2000

// LDS layout (bytes). x tile: 148 cols (halo 10/10), 16 ch (pad to 24 halves)
#define XSTRIDE 24
#define XCOLS   148
#define XOFF    0
#define XSZ     (XCOLS * XSTRIDE * 2)          // 7104 B
#define HWIN    144                            // h1/h2 window: [t0-8, t0+136)
#define H1OFF   XSZ
#define HSZ     (HWIN * 64 * 2)                // 18432 B
#define H2OFF   (H1OFF + HSZ)
#define SMEM_BYTES (H2OFF + HSZ)               // 43968 B
#define H3OFF   H1OFF                          // h3 aliases h1 (dead after L2)
#define H3STRIDE 40                            // halfs per col (32 used + pad)

// packed weight fragments: [f][frag*2+mw][lane] of half8 (16B each)
#define NFRAG   36
#define PW_HALF8_PER_F (NFRAG * 2 * 64)
#define PW_BYTES ((size_t)F_BINS * PW_HALF8_PER_F * 16)   // ~18.9 MB

typedef _Float16 half8  __attribute__((ext_vector_type(8)));
typedef _Float16 half2t __attribute__((ext_vector_type(2)));
typedef float    f32x4  __attribute__((ext_vector_type(4)));

#define MFMA16(a, b, c) __builtin_amdgcn_mfma_f32_16x16x32_f16(a, b, c, 0, 0, 0)

// frag ids: a1[hr][p] = hr*3+p (0..5); a2[w][hr][kk] = 6+w*4+hr*2+kk (6..25);
//           a3[w][kk] = 26+w*2+kk (26..35)
__device__ __forceinline__ half8 gather_frag(
    int f, int frag, int mw, int lane,
    const float* __restrict__ Wr1, const float* __restrict__ Wi1,
    const float* __restrict__ Wr2, const float* __restrict__ Wi2,
    const float* __restrict__ Wr3, const float* __restrict__ Wi3)
{
    const int g = lane >> 4, r16 = lane & 15;
    half8 v;
    if (frag < 6) {
        int hr = frag / 3, p = frag % 3;
        int tap = 2 * p + (g >> 1);
        #pragma unroll
        for (int j = 0; j < 8; ++j) {
            float val = 0.f;
            if (tap < KW) {
                long idx = (((long)f * HCH + hr * 16 + r16) * NCH + j) * KW + tap;
                if (mw == 0) val = (g & 1) ? -Wi1[idx] : Wr1[idx];
                else         val = (g & 1) ?  Wr1[idx] : Wi1[idx];
            }
            v[j] = (_Float16)val;
        }
    } else if (frag < 26) {
        int u = frag - 6;
        int w = u >> 2, hr = (u >> 1) & 1, kk = u & 1;
        #pragma unroll
        for (int j = 0; j < 8; ++j) {
            int c = g * 8 + j;
            long idx = (((long)f * HCH + hr * 16 + r16) * HCH + c) * KW + w;
            float val;
            if (mw == 0) val = kk ? -Wi2[idx] : Wr2[idx];
            else         val = kk ?  Wr2[idx] : Wi2[idx];
            v[j] = (_Float16)val;
        }
    } else {
        int u = frag - 26;
        int w = u >> 1, kk = u & 1;
        #pragma unroll
        for (int j = 0; j < 8; ++j) {
            int c = g * 8 + j;
            long idx = (((long)f * (NCH * NSRC) + r16) * HCH + c) * KW + w;
            float val;
            if (mw == 0) val = kk ? -Wi3[idx] : Wr3[idx];
            else         val = kk ?  Wr3[idx] : Wi3[idx];
            v[j] = (_Float16)val;
        }
    }
    return v;
}

__global__ __launch_bounds__(256) void repack_kernel(
    const float* __restrict__ Wr1, const float* __restrict__ Wi1,
    const float* __restrict__ Wr2, const float* __restrict__ Wi2,
    const float* __restrict__ Wr3, const float* __restrict__ Wi3,
    _Float16* __restrict__ pw)
{
    const int bid  = blockIdx.x;
    const int f    = bid >> 2;
    const int part = bid & 3;
    const int lane = threadIdx.x & 63;
    const int q    = threadIdx.x >> 6;
    half8* pwv = (half8*)pw;
    for (int u = part * 18 + q; u < part * 18 + 18; u += 4) {
        int frag = u >> 1, mw = u & 1;
        half8 v = gather_frag(f, frag, mw, lane, Wr1, Wi1, Wr2, Wi2, Wr3, Wi3);
        pwv[((size_t)f * (NFRAG * 2) + u) * 64 + lane] = v;
    }
}

template<bool PACKED>
__global__ __launch_bounds__(256, 3) void cddcnn_mfma_kernel(
    const float* __restrict__ x,
    const float* __restrict__ Wr1, const float* __restrict__ Wi1,
    const float* __restrict__ Wr2, const float* __restrict__ Wi2,
    const float* __restrict__ Wr3, const float* __restrict__ Wi3,
    float* __restrict__ out, const _Float16* __restrict__ pw)
{
    __shared__ __align__(16) char sm[SMEM_BYTES];

    const int tid  = threadIdx.x;
    const int lane = tid & 63;
    const int wv   = tid >> 6;      // wave id 0..3 -> column-block owner
    const int g    = lane >> 4;
    const int r16  = lane & 15;

    const int bid = blockIdx.x;
    const int tl  = bid % NTILES;
    const int f   = (bid / NTILES) % F_BINS;
    const int b   = bid / (NTILES * F_BINS);
    const int t0  = tl * TT;
    const bool interior = (tl >= 1) && (tl <= 14);

    // column ownership: L1/L2 col-blocks {wv, wv+4, wv+8(<9)}, L3 {wv, wv+4}
    const int ncb = (wv == 0) ? 3 : 2;

    const half8* pwf = PACKED ? ((const half8*)pw) + (size_t)f * PW_HALF8_PER_F + lane
                              : nullptr;
    #define LOADFRAG(fr, mww) (PACKED ? pwf[((fr) * 2 + (mww)) * 64] \
                  : gather_frag(f, (fr), (mww), lane, Wr1, Wi1, Wr2, Wi2, Wr3, Wi3))

    const long xr_base = ((long)(b * 2 * F_BINS + f) * NCH) * TLEN;
    const long xi_base = ((long)(b * 2 * F_BINS + F_BINS + f) * NCH) * TLEN;

    // ---- Phase X: stage x tile as fp16 [148 cols][16 ch], halo 10 ----
    for (int e = tid; e < XCOLS * 16; e += 256) {
        int pc  = e / XCOLS;
        int idx = e - pc * XCOLS;
        int t   = t0 - 10 + idx;
        float val = 0.f;
        if (t >= 0 && t < TLEN) {
            long base = (pc < 8) ? (xr_base + (long)pc * TLEN)
                                 : (xi_base + (long)(pc - 8) * TLEN);
            val = x[base + t];
        }
        *(_Float16*)(sm + XOFF + (idx * XSTRIDE + pc) * 2) = (_Float16)val;
    }
    __syncthreads();

    // per-lane address constants
    const int colb0 = wv * 16 + r16;          // col at cb=0
    const int Xc    = (r16 & 7) << 4;         // write-swizzle XOR (col&7 == r16&7)
    // epilogue write offsets: ((mw*64 + hr*32 + g*8 + q*4) ^ Xc), hoisted
    int woff[2][2][2];
    #pragma unroll
    for (int mw = 0; mw < 2; ++mw)
    #pragma unroll
    for (int hr = 0; hr < 2; ++hr)
    #pragma unroll
    for (int q = 0; q < 2; ++q)
        woff[mw][hr][q] = ((mw * 64 + hr * 32 + g * 8 + q * 4) ^ Xc);

    // shared epilogue: write relu(acc) (or raw) as fp16 into H-buffer
    auto epi = [&](int HOFF, f32x4 (&acc)[3][2][2], bool check) {
        char* wb = sm + HOFF + colb0 * 128;
        #pragma unroll
        for (int cb = 0; cb < 3; ++cb) {
            if (cb < ncb) {
                bool ok = true;
                if (check) {
                    int t = t0 - 8 + colb0 + 64 * cb;
                    ok = (t >= 0) && (t < TLEN);
                }
                #pragma unroll
                for (int mw = 0; mw < 2; ++mw)
                #pragma unroll
                for (int hr = 0; hr < 2; ++hr)
                #pragma unroll
                for (int q = 0; q < 2; ++q) {
                    float v0 = ok ? fmaxf(acc[cb][mw][hr][2 * q],     0.f) : 0.f;
                    float v1 = ok ? fmaxf(acc[cb][mw][hr][2 * q + 1], 0.f) : 0.f;
                    half2t hv; hv[0] = (_Float16)v0; hv[1] = (_Float16)v1;
                    *(half2t*)(wb + cb * 8192 + woff[mw][hr][q]) = hv;
                }
            }
        }
    };

    // ---- Phase L1: h1 = relu(cconv(x, W1)) over 144-col window ----
    {
        half8 a1[2][2][3];   // [mw][hr][p]
        #pragma unroll
        for (int mw = 0; mw < 2; ++mw)
        #pragma unroll
        for (int hr = 0; hr < 2; ++hr)
        #pragma unroll
        for (int p = 0; p < 3; ++p)
            a1[mw][hr][p] = LOADFRAG(hr * 3 + p, mw);

        f32x4 acc[3][2][2] = {};
        const char* xb = sm + XOFF + colb0 * 48 + (g & 1) * 16;
        #pragma unroll
        for (int p = 0; p < 3; ++p) {
            int tap = 2 * p + (g >> 1);
            if (tap > 4) tap = 4;          // A is zero for these groups
            const char* xbp = xb + tap * 48;
            #pragma unroll
            for (int cb = 0; cb < 3; ++cb) {
                if (cb < ncb) {
                    const half8 bf = *(const half8*)(xbp + cb * 3072);
                    #pragma unroll
                    for (int mw = 0; mw < 2; ++mw)
                    #pragma unroll
                    for (int hr = 0; hr < 2; ++hr)
                        acc[cb][mw][hr] = MFMA16(a1[mw][hr][p], bf, acc[cb][mw][hr]);
                }
            }
        }
        epi(H1OFF, acc, !interior);
    }
    __syncthreads();

    // ---- Phase L2: h2 = relu(cconv(h1, W2)) over 144-col window ----
    {
        f32x4 acc[3][2][2] = {};
        #pragma unroll
        for (int w = 0; w < KW; ++w)
        #pragma unroll
        for (int kk = 0; kk < 2; ++kk) {
            half8 a2[2][2];   // [mw][hr]
            #pragma unroll
            for (int mw = 0; mw < 2; ++mw)
            #pragma unroll
            for (int hr = 0; hr < 2; ++hr)
                a2[mw][hr] = LOADFRAG(6 + w * 4 + hr * 2 + kk, mw);

            const int sc0 = colb0 + w - 2;
            const char* rb = sm + H1OFF + sc0 * 128
                           + (((kk * 64 + g * 16)) ^ ((sc0 & 7) << 4));
            #pragma unroll
            for (int cb = 0; cb < 3; ++cb) {
                if (cb < ncb) {
                    const half8 bf = *(const half8*)(rb + cb * 8192);
                    #pragma unroll
                    for (int mw = 0; mw < 2; ++mw)
                    #pragma unroll
                    for (int hr = 0; hr < 2; ++hr)
                        acc[cb][mw][hr] = MFMA16(a2[mw][hr], bf, acc[cb][mw][hr]);
                }
            }
        }
        epi(H2OFF, acc, !interior);
    }
    __syncthreads();

    // ---- Phase L3: h3 = cconv(h2, W3) (no relu), 128 cols, blocks {wv, wv+4} ----
    {
        f32x4 acc3[2][2] = {};   // [cb3][mw]
        #pragma unroll
        for (int w = 0; w < KW; ++w)
        #pragma unroll
        for (int kk = 0; kk < 2; ++kk) {
            half8 a3[2];
            #pragma unroll
            for (int mw = 0; mw < 2; ++mw)
                a3[mw] = LOADFRAG(26 + w * 2 + kk, mw);

            const int sc0 = colb0 + 6 + w;
            const char* rb = sm + H2OFF + sc0 * 128
                           + (((kk * 64 + g * 16)) ^ ((sc0 & 7) << 4));
            #pragma unroll
            for (int cb = 0; cb < 2; ++cb) {
                const half8 bf = *(const half8*)(rb + cb * 8192);
                #pragma unroll
                for (int mw = 0; mw < 2; ++mw)
                    acc3[cb][mw] = MFMA16(a3[mw], bf, acc3[cb][mw]);
            }
        }
        char* wb3 = sm + H3OFF + colb0 * 80 + g * 8;
        #pragma unroll
        for (int cb = 0; cb < 2; ++cb)
        #pragma unroll
        for (int mw = 0; mw < 2; ++mw)
        #pragma unroll
        for (int q = 0; q < 2; ++q) {
            half2t hv;
            hv[0] = (_Float16)acc3[cb][mw][2 * q];
            hv[1] = (_Float16)acc3[cb][mw][2 * q + 1];
            *(half2t*)(wb3 + cb * 5120 + mw * 32 + q * 4) = hv;
        }
    }
    __syncthreads();

    // ---- Phase M: mask multiply + channel reduce + store (all 256 threads) ----
    {
        int s   = tid >> 7;         // 0..1
        int col = tid & 127;
        int t = t0 + col;
        if (t < TLEN) {
            const half8 xrv = *(const half8*)(sm + XOFF + ((col + 10) * XSTRIDE + 0) * 2);
            const half8 xiv = *(const half8*)(sm + XOFF + ((col + 10) * XSTRIDE + 8) * 2);
            half8 h3q[4];
            #pragma unroll
            for (int q = 0; q < 4; ++q)
                h3q[q] = *(const half8*)(sm + H3OFF + col * (H3STRIDE * 2) + q * 16);
            float Yr = 0.f, Yi = 0.f;
            #pragma unroll
            for (int c = 0; c < NCH; ++c) {
                float vr = (float)xrv[c];
                float vi = (float)xiv[c];
                int o = 2 * c + s;
                float hr = (c < 4) ? (float)h3q[0][o] : (float)h3q[1][o - 8];
                float hi = (c < 4) ? (float)h3q[2][o] : (float)h3q[3][o - 8];
                Yr += vr * hr - vi * hi;
                Yi += vr * hi + vi * hr;
            }
            out[((long)(b * 2 * F_BINS + f) * NSRC + s) * TLEN + t]          = Yr;
            out[((long)(b * 2 * F_BINS + F_BINS + f) * NSRC + s) * TLEN + t] = Yi;
        }
    }
}

extern "C" void kernel_launch(void* const* d_in, const int* in_sizes, int n_in,
                              void* d_out, int out_size, void* d_ws, size_t ws_size,
                              hipStream_t stream) {
    const float* x   = (const float*)d_in[0];
    const float* Wr1 = (const float*)d_in[1];
    const float* Wi1 = (const float*)d_in[2];
    const float* Wr2 = (const float*)d_in[3];
    const float* Wi2 = (const float*)d_in[4];
    const float* Wr3 = (const float*)d_in[5];
    const float* Wi3 = (const float*)d_in[6];
    float* out = (float*)d_out;

    dim3 block(256);
    dim3 grid(BATCH * F_BINS * NTILES);
    if (ws_size >= PW_BYTES) {
        _Float16* pw = (_Float16*)d_ws;
        repack_kernel<<<F_BINS * 4, block, 0, stream>>>(Wr1, Wi1, Wr2, Wi2, Wr3, Wi3, pw);
        cddcnn_mfma_kernel<true><<<grid, block, 0, stream>>>(
            x, Wr1, Wi1, Wr2, Wi2, Wr3, Wi3, out, pw);
    } else {
        cddcnn_mfma_kernel<false><<<grid, block, 0, stream>>>(
            x, Wr1, Wi1, Wr2, Wi2, Wr3, Wi3, out, nullptr);
    }
}